// Round 12
// baseline (474.282 us; speedup 1.0000x reference)
//
#include <hip/hip_runtime.h>
#include <math.h>

#define BB 32
#define HH 16
#define DD 256
#define RDIM 64
#define NEMB 4096
#define NINT 16384
#define NSLOTS 32768
#define KVLEN 1024
#define LNEPS 1e-5f
#define NCH 16
#define CH 64
#define CAP 20

// ---- K0: LayerNorm (blocks 0..31) + slot-count init (blocks 32..159) ----
__global__ __launch_bounds__(256) void ln_init_kernel(const float* __restrict__ x,
    const float* __restrict__ lw, const float* __restrict__ lb,
    float* __restrict__ hT, int* __restrict__ cnt)
{
    int t = threadIdx.x;
    if (blockIdx.x >= BB) {
        int i = (blockIdx.x - BB) * 256 + t;
        if (i < NSLOTS) cnt[i] = 0;
        return;
    }
    int b = blockIdx.x;
    const float* row = x + (size_t)b * NEMB;
    float4 v[4];
    float sum = 0.f, sq = 0.f;
#pragma unroll
    for (int j = 0; j < 4; ++j) {
        v[j] = *(const float4*)(row + t * 4 + j * 1024);
        sum += v[j].x + v[j].y + v[j].z + v[j].w;
        sq += v[j].x * v[j].x + v[j].y * v[j].y + v[j].z * v[j].z + v[j].w * v[j].w;
    }
    __shared__ float s1[4], s2[4];
#pragma unroll
    for (int o = 32; o > 0; o >>= 1) {
        sum += __shfl_xor(sum, o, 64);
        sq += __shfl_xor(sq, o, 64);
    }
    int wave = t >> 6, lane = t & 63;
    if (lane == 0) { s1[wave] = sum; s2[wave] = sq; }
    __syncthreads();
    sum = s1[0] + s1[1] + s1[2] + s1[3];
    sq = s2[0] + s2[1] + s2[2] + s2[3];
    float mu = sum / NEMB;
    float var = sq / NEMB - mu * mu;
    float rstd = rsqrtf(var + LNEPS);
#pragma unroll
    for (int j = 0; j < 4; ++j) {
        int n = t * 4 + j * 1024;
        float4 wv = *(const float4*)(lw + n);
        float4 bv = *(const float4*)(lb + n);
        hT[(size_t)(n + 0) * BB + b] = (v[j].x - mu) * rstd * wv.x + bv.x;
        hT[(size_t)(n + 1) * BB + b] = (v[j].y - mu) * rstd * wv.y + bv.y;
        hT[(size_t)(n + 2) * BB + b] = (v[j].z - mu) * rstd * wv.z + bv.z;
        hT[(size_t)(n + 3) * BB + b] = (v[j].w - mu) * rstd * wv.w + bv.w;
    }
}

// ---------------- shared GEMM body (256 threads): thread = 2n x 32m ----------------
__device__ __forceinline__ void gemm_body(const float* __restrict__ AT,
    const float* __restrict__ W, float* __restrict__ P,
    int N, int kChunk, int x, int s)
{
    int n = (x * 256 + threadIdx.x) * 2;
    size_t k0 = (size_t)s * kChunk;
    float2 acc[32];
#pragma unroll
    for (int mi = 0; mi < 32; ++mi) acc[mi] = make_float2(0.f, 0.f);
    const float* w = W + k0 * N + n;
    const float* a = AT + k0 * 32;
#pragma unroll 4
    for (int kk = 0; kk < kChunk; ++kk) {
        float2 wv = *(const float2*)w;
#pragma unroll
        for (int mi = 0; mi < 32; ++mi) {
            float am = a[mi];
            acc[mi].x = fmaf(am, wv.x, acc[mi].x);
            acc[mi].y = fmaf(am, wv.y, acc[mi].y);
        }
        w += N;
        a += 32;
    }
    float* p = P + ((size_t)s * 32) * N + n;
#pragma unroll
    for (int mi = 0; mi < 32; ++mi)
        *(float2*)(p + (size_t)mi * N) = acc[mi];
}

// ---------------- 64-thread GEMM body: thread = 2n x 32m ----------------
__device__ __forceinline__ void gemm_body64(const float* __restrict__ AT,
    const float* __restrict__ W, float* __restrict__ P,
    int N, int kChunk, int x, int s)
{
    int n = (x * 64 + threadIdx.x) * 2;
    size_t k0 = (size_t)s * kChunk;
    float2 acc[32];
#pragma unroll
    for (int mi = 0; mi < 32; ++mi) acc[mi] = make_float2(0.f, 0.f);
    const float* w = W + k0 * N + n;
    const float* a = AT + k0 * 32;
#pragma unroll 4
    for (int kk = 0; kk < kChunk; ++kk) {
        float2 wv = *(const float2*)w;
#pragma unroll
        for (int mi = 0; mi < 32; ++mi) {
            float am = a[mi];
            acc[mi].x = fmaf(am, wv.x, acc[mi].x);
            acc[mi].y = fmaf(am, wv.y, acc[mi].y);
        }
        w += N;
        a += 32;
    }
    float* p = P + ((size_t)s * 32) * N + n;
#pragma unroll
    for (int mi = 0; mi < 32; ++mi)
        *(float2*)(p + (size_t)mi * N) = acc[mi];
}

// ---- K1: QKV gemm (768) + fc_in gemm (512) + K-map build (128) ----
__global__ __launch_bounds__(256) void phase2_kernel(const float* __restrict__ hT,
    const float* __restrict__ wq, const float* __restrict__ wk, const float* __restrict__ wv,
    float* __restrict__ Pq, const float* __restrict__ fciw, float* __restrict__ P1,
    const int* __restrict__ kidx, int* __restrict__ cnt, int* __restrict__ ent)
{
    int id = blockIdx.x;
    if (id < 768) {
        int w = id >> 8;
        const float* W = (w == 0) ? wq : (w == 1) ? wk : wv;
        float* Pz = Pq + (size_t)w * ((size_t)32 * 32 * NEMB);
        gemm_body(hT, W, Pz, NEMB, 128, id & 7, (id >> 3) & 31);
    } else if (id < 1280) {
        id -= 768;
        gemm_body(hT, fciw, P1, NINT, 256, id & 31, id >> 5);
    } else {
        int i = (id - 1280) * 256 + threadIdx.x;   // (b,l) flat
        int s = kidx[i];
        int pos = atomicAdd(&cnt[s], 1);
        if (pos < CAP) ent[s * CAP + pos] = i;     // i = b*1024 + l
    }
}

__device__ inline float gelu_tanh(float x)
{
    float x3 = x * x * x;
    return 0.5f * x * (1.f + tanhf(0.7978845608028654f * (x + 0.044715f * x3)));
}

// ---- K2: QKV reduce+RoPE (768) + fc_in reduce+gelu (2048) ----
__global__ __launch_bounds__(256) void phase3_kernel(const float* __restrict__ Pq,
    float* __restrict__ q, float* __restrict__ k, float* __restrict__ v,
    const int* __restrict__ pos,
    const float* __restrict__ P1, const float* __restrict__ fcib, float* __restrict__ mT)
{
    int id = blockIdx.x, t = threadIdx.x;
    if (id < 768) {
        int w = id >> 8;
        int m = (id >> 3) & 31;
        int n0 = ((id & 7) * 256 + t) * 2;
        const float* p = Pq + (size_t)w * ((size_t)32 * 32 * NEMB) + (size_t)m * NEMB + n0;
        float sx = 0.f, sy = 0.f;
#pragma unroll 4
        for (int i = 0; i < 32; ++i) {
            float2 u = *(const float2*)p;
            sx += u.x; sy += u.y;
            p += (size_t)32 * NEMB;
        }
        int d = n0 & (DD - 1);
        if (w < 2 && d < RDIM) {
            int i = d >> 1;
            float fr = exp2f((float)i * (-13.287712379549449f / 32.f)); // 10000^(-i/32)
            float ang = (float)pos[m] * fr;
            float sn, cs;
            sincosf(ang, &sn, &cs);
            float x1 = sx, x2 = sy;
            sx = x1 * cs - x2 * sn;
            sy = x2 * cs + x1 * sn;
        }
        float* o = (w == 0) ? q : (w == 1) ? k : v;
        *(float2*)(o + (size_t)m * NEMB + n0) = make_float2(sx, sy);
    } else {
        int j = id - 768;
        int m = j >> 6;
        int n = (j & 63) * 256 + t;
        const float* p = P1 + (size_t)m * NINT + n;
        float s = 0.f;
#pragma unroll 4
        for (int i = 0; i < 16; ++i) { s += *p; p += (size_t)32 * NINT; }
        mT[(size_t)n * 32 + m] = gelu_tanh(s + fcib[n]);
    }
}

// ---- K3: streaming QK scores — block = one K-cache slot, sequential sweep ----
__global__ __launch_bounds__(256) void scores_kernel(const float* __restrict__ q,
    const float* __restrict__ knew, const float* __restrict__ kcache,
    const int* __restrict__ nkl, const int* __restrict__ cnt, const int* __restrict__ ent,
    const float* __restrict__ mask, float* __restrict__ scores)
{
    int s = blockIdx.x;
    int n = cnt[s];
    if (n == 0) return;
    if (n > CAP) n = CAP;
    int t = threadIdx.x;
    int h = t >> 4, u = t & 15;
    const float* row = kcache + (size_t)s * NEMB;
#pragma unroll
    for (int j = 0; j < BB; ++j)
        if (nkl[j] == s) row = knew + (size_t)j * NEMB;
    float4 kf[4];
    const float* rp = row + h * DD + u * 16;
#pragma unroll
    for (int j = 0; j < 4; ++j) kf[j] = *(const float4*)(rp + j * 4);
    for (int e = 0; e < n; ++e) {
        int bl = ent[s * CAP + e];
        int b = bl >> 10, l = bl & 1023;
        const float* qp = q + (size_t)b * NEMB + h * DD + u * 16;
        float d = 0.f;
#pragma unroll
        for (int j = 0; j < 4; ++j) {
            float4 qf = *(const float4*)(qp + j * 4);
            d = fmaf(kf[j].x, qf.x, fmaf(kf[j].y, qf.y, fmaf(kf[j].z, qf.z, fmaf(kf[j].w, qf.w, d))));
        }
        d += __shfl_xor(d, 8, 64);
        d += __shfl_xor(d, 4, 64);
        d += __shfl_xor(d, 2, 64);
        d += __shfl_xor(d, 1, 64);
        if (u == 0) scores[((size_t)b * HH + h) * KVLEN + l] = d * 0.0625f + mask[b * KVLEN + l];
    }
}

// ---- K4: fc_out gemm (2048 blocks, FIRST) + PV attention (8192 1-wave blocks) ----
__global__ __launch_bounds__(64) void phase4_kernel(
    const float* __restrict__ vnew, const float* __restrict__ vcache,
    const int* __restrict__ vidx, const int* __restrict__ nvl,
    const float* __restrict__ scores, float* __restrict__ pctx,
    const float* __restrict__ mT, const float* __restrict__ fcow, float* __restrict__ P2)
{
    int id = blockIdx.x;
    int t = threadIdx.x;
    if (id < 2048) {
        // fc_out: N=4096, K=16384; x in [0,32), s in [0,64) chunk 256
        gemm_body64(mT, fcow, P2, NEMB, 256, id & 31, id >> 5);
        return;
    }
    id -= 2048;
    int bh = id >> 4, c = id & 15;
    int b = bh >> 4, h = bh & 15;

    __shared__ const float* vparr[CH];

    // lane = one KV row: V pointer setup with cache-override scan
    {
        int vs = vidx[b * KVLEN + c * CH + t];
        const float* vbase = vcache + (size_t)vs * NEMB;
#pragma unroll
        for (int j = 0; j < BB; ++j)
            if (nvl[j] == vs) vbase = vnew + (size_t)j * NEMB;
        vparr[t] = vbase + (size_t)h * DD;
    }

    // global softmax stats from the full scores row (16 elems/thread)
    const float* sr = scores + (size_t)bh * KVLEN;
    float4 s4[4];
    const float* sp = sr + t * 16;
#pragma unroll
    for (int j = 0; j < 4; ++j) s4[j] = *(const float4*)(sp + j * 4);
    float mx = -INFINITY;
#pragma unroll
    for (int j = 0; j < 4; ++j)
        mx = fmaxf(mx, fmaxf(fmaxf(s4[j].x, s4[j].y), fmaxf(s4[j].z, s4[j].w)));
#pragma unroll
    for (int o = 32; o > 0; o >>= 1) mx = fmaxf(mx, __shfl_xor(mx, o, 64));
    float sm = 0.f;
#pragma unroll
    for (int j = 0; j < 4; ++j)
        sm += expf(s4[j].x - mx) + expf(s4[j].y - mx) + expf(s4[j].z - mx) + expf(s4[j].w - mx);
#pragma unroll
    for (int o = 32; o > 0; o >>= 1) sm += __shfl_xor(sm, o, 64);
    float inv = 1.f / sm;
    // this thread's row weight (row = c*CH + t), normalized
    float e = expf(sr[c * CH + t] - mx) * inv;
    __syncthreads();

    // PV: lane owns d = t*4..t*4+3; V row pointer broadcast from LDS, weight from shfl
    float4 a4 = make_float4(0.f, 0.f, 0.f, 0.f);
#pragma unroll 8
    for (int l = 0; l < CH; ++l) {
        const float* vr = vparr[l];
        float4 vf = *(const float4*)(vr + t * 4);
        float pw = __shfl(e, l, 64);
        a4.x = fmaf(pw, vf.x, a4.x);
        a4.y = fmaf(pw, vf.y, a4.y);
        a4.z = fmaf(pw, vf.z, a4.z);
        a4.w = fmaf(pw, vf.w, a4.w);
    }

    int pi = bh * NCH + c;
    *(float4*)(pctx + (size_t)pi * DD + t * 4) = a4;
}

// ---- K5: attention combine = plain sum of 16 normalized partials ----
__global__ __launch_bounds__(256) void attn_comb_kernel(const float* __restrict__ pctx,
    float* __restrict__ ctxT)
{
    int bh = blockIdx.x;
    int b = bh >> 4, h = bh & 15;
    int t = threadIdx.x;
    float acc = 0.f;
#pragma unroll
    for (int c = 0; c < NCH; ++c)
        acc += pctx[((size_t)bh * NCH + c) * DD + t];
    ctxT[((size_t)h * DD + t) * BB + b] = acc;
}

// ---- K6: Wo gemm (512) + fc_out reduce -> mlp_tmp (512) ----
__global__ __launch_bounds__(256) void phase6_kernel(const float* __restrict__ ctxT,
    const float* __restrict__ wo, float* __restrict__ P0,
    const float* __restrict__ P2, const float* __restrict__ fcob,
    const float* __restrict__ resid, float* __restrict__ mlp_tmp)
{
    int id = blockIdx.x, t = threadIdx.x;
    if (id < 512) {
        gemm_body(ctxT, wo, P0, NEMB, 64, id & 7, id >> 3);
    } else {
        int j = id - 512;
        int m = j >> 4;
        int n = (j & 15) * 256 + t;
        const float* p = P2 + (size_t)m * NEMB + n;
        float s = 0.f;
#pragma unroll 4
        for (int i = 0; i < 64; ++i) { s += *p; p += (size_t)32 * NEMB; }
        mlp_tmp[(size_t)m * NEMB + n] = s + fcob[n] + resid[(size_t)m * NEMB + n];
    }
}

// ---- K7: Wo reduce + mlp_tmp -> out (512) ----
__global__ __launch_bounds__(256) void phase7_kernel(const float* __restrict__ P0,
    const float* __restrict__ mlp_tmp, float* __restrict__ out)
{
    int n = blockIdx.x * 256 + threadIdx.x;
    int m = blockIdx.y;
    const float* p = P0 + (size_t)m * NEMB + n;
    float s = 0.f;
#pragma unroll 4
    for (int i = 0; i < 64; ++i) { s += *p; p += (size_t)32 * NEMB; }
    out[(size_t)m * NEMB + n] = s + mlp_tmp[(size_t)m * NEMB + n];
}

extern "C" void kernel_launch(void* const* d_in, const int* in_sizes, int n_in,
                              void* d_out, int out_size, void* d_ws, size_t ws_size,
                              hipStream_t stream)
{
    (void)in_sizes; (void)n_in; (void)out_size; (void)ws_size;
    const float* hs      = (const float*)d_in[0];
    const float* kcache  = (const float*)d_in[1];
    const float* vcache  = (const float*)d_in[2];
    const float* ln_w    = (const float*)d_in[3];
    const float* ln_b    = (const float*)d_in[4];
    const float* wq      = (const float*)d_in[5];
    const float* wk      = (const float*)d_in[6];
    const float* wv      = (const float*)d_in[7];
    const float* wo      = (const float*)d_in[8];
    const float* fc_in_w = (const float*)d_in[9];
    const float* fc_in_b = (const float*)d_in[10];
    const float* fc_out_w= (const float*)d_in[11];
    const float* fc_out_b= (const float*)d_in[12];
    const float* mask    = (const float*)d_in[13];
    const int* nkl       = (const int*)d_in[14];
    const int* nvl       = (const int*)d_in[15];
    const int* kidx      = (const int*)d_in[16];
    const int* vidx      = (const int*)d_in[17];
    const int* pos       = (const int*)d_in[18];
    float* out = (float*)d_out;

    char* ws = (char*)d_ws;
    float* hT      = (float*)ws; ws += (size_t)NEMB * BB * 4;
    float* qb      = (float*)ws; ws += (size_t)BB * NEMB * 4;
    float* kb      = (float*)ws; ws += (size_t)BB * NEMB * 4;
    float* vb      = (float*)ws; ws += (size_t)BB * NEMB * 4;
    float* ctxT    = (float*)ws; ws += (size_t)NEMB * BB * 4;
    float* mlp_tmp = (float*)ws; ws += (size_t)BB * NEMB * 4;
    float* mT      = (float*)ws; ws += (size_t)NINT * BB * 4;
    int*   cnt     = (int*)ws;   ws += (size_t)NSLOTS * 4;               // 128 KB
    int*   ent     = (int*)ws;   ws += (size_t)NSLOTS * CAP * 4;         // 2.6 MB
    float* scores  = (float*)ws; ws += (size_t)BB * HH * KVLEN * 4;      // 2 MB
    float* pctx    = (float*)ws; ws += (size_t)BB * HH * NCH * DD * 4;   // 8.4 MB
    float* Pq      = (float*)ws; ws += (size_t)3 * 32 * 32 * NEMB * 4;   // 50.3 MB
    float* P0      = (float*)ws; ws += (size_t)64 * 32 * NEMB * 4;       // 33.6 MB
    float* P1      = (float*)ws; ws += (size_t)16 * 32 * NINT * 4;       // 33.6 MB
    float* P2      = (float*)ws;                                          // 33.6 MB

    ln_init_kernel<<<160, 256, 0, stream>>>(hs, ln_w, ln_b, hT, cnt);

    phase2_kernel<<<1408, 256, 0, stream>>>(hT, wq, wk, wv, Pq, fc_in_w, P1,
                                            kidx, cnt, ent);

    phase3_kernel<<<2816, 256, 0, stream>>>(Pq, qb, kb, vb, pos, P1, fc_in_b, mT);

    scores_kernel<<<NSLOTS, 256, 0, stream>>>(qb, kb, kcache, nkl, cnt, ent,
                                              mask, scores);

    phase4_kernel<<<10240, 64, 0, stream>>>(vb, vcache, vidx, nvl,
                                            scores, pctx, mT, fc_out_w, P2);

    attn_comb_kernel<<<BB * HH, 256, 0, stream>>>(pctx, ctxT);

    phase6_kernel<<<1024, 256, 0, stream>>>(ctxT, wo, P0, P2, fc_out_b, hs, mlp_tmp);

    phase7_kernel<<<dim3(16, 32), 256, 0, stream>>>(P0, mlp_tmp, out);
}

// Round 13
// 444.778 us; speedup vs baseline: 1.0663x; 1.0663x over previous
//
#include <hip/hip_runtime.h>
#include <math.h>

#define BB 32
#define HH 16
#define DD 256
#define RDIM 64
#define NEMB 4096
#define NINT 16384
#define NSLOTS 32768
#define KVLEN 1024
#define LNEPS 1e-5f
#define NCH 16
#define CH 64

// ---------------- LayerNorm -> hT [NE][32] (A-transposed for GEMM) ----------------
__global__ __launch_bounds__(256) void ln_kernel(const float* __restrict__ x,
    const float* __restrict__ lw, const float* __restrict__ lb,
    float* __restrict__ hT)
{
    int b = blockIdx.x;
    int t = threadIdx.x;
    const float* row = x + (size_t)b * NEMB;
    float4 v[4];
    float sum = 0.f, sq = 0.f;
#pragma unroll
    for (int j = 0; j < 4; ++j) {
        v[j] = *(const float4*)(row + t * 4 + j * 1024);
        sum += v[j].x + v[j].y + v[j].z + v[j].w;
        sq += v[j].x * v[j].x + v[j].y * v[j].y + v[j].z * v[j].z + v[j].w * v[j].w;
    }
    __shared__ float s1[4], s2[4];
#pragma unroll
    for (int o = 32; o > 0; o >>= 1) {
        sum += __shfl_xor(sum, o, 64);
        sq += __shfl_xor(sq, o, 64);
    }
    int wave = t >> 6, lane = t & 63;
    if (lane == 0) { s1[wave] = sum; s2[wave] = sq; }
    __syncthreads();
    sum = s1[0] + s1[1] + s1[2] + s1[3];
    sq = s2[0] + s2[1] + s2[2] + s2[3];
    float mu = sum / NEMB;
    float var = sq / NEMB - mu * mu;
    float rstd = rsqrtf(var + LNEPS);
#pragma unroll
    for (int j = 0; j < 4; ++j) {
        int n = t * 4 + j * 1024;
        float4 wv = *(const float4*)(lw + n);
        float4 bv = *(const float4*)(lb + n);
        hT[(size_t)(n + 0) * BB + b] = (v[j].x - mu) * rstd * wv.x + bv.x;
        hT[(size_t)(n + 1) * BB + b] = (v[j].y - mu) * rstd * wv.y + bv.y;
        hT[(size_t)(n + 2) * BB + b] = (v[j].z - mu) * rstd * wv.z + bv.z;
        hT[(size_t)(n + 3) * BB + b] = (v[j].w - mu) * rstd * wv.w + bv.w;
    }
}

// ---------------- shared GEMM body (256 threads): thread = 2n x 32m ----------------
__device__ __forceinline__ void gemm_body(const float* __restrict__ AT,
    const float* __restrict__ W, float* __restrict__ P,
    int N, int kChunk, int x, int s)
{
    int n = (x * 256 + threadIdx.x) * 2;
    size_t k0 = (size_t)s * kChunk;
    float2 acc[32];
#pragma unroll
    for (int mi = 0; mi < 32; ++mi) acc[mi] = make_float2(0.f, 0.f);
    const float* w = W + k0 * N + n;
    const float* a = AT + k0 * 32;
#pragma unroll 4
    for (int kk = 0; kk < kChunk; ++kk) {
        float2 wv = *(const float2*)w;
#pragma unroll
        for (int mi = 0; mi < 32; ++mi) {
            float am = a[mi];
            acc[mi].x = fmaf(am, wv.x, acc[mi].x);
            acc[mi].y = fmaf(am, wv.y, acc[mi].y);
        }
        w += N;
        a += 32;
    }
    float* p = P + ((size_t)s * 32) * N + n;
#pragma unroll
    for (int mi = 0; mi < 32; ++mi)
        *(float2*)(p + (size_t)mi * N) = acc[mi];
}

// ---------------- 64-thread GEMM body: thread = 2n x 32m ----------------
__device__ __forceinline__ void gemm_body64(const float* __restrict__ AT,
    const float* __restrict__ W, float* __restrict__ P,
    int N, int kChunk, int x, int s)
{
    int n = (x * 64 + threadIdx.x) * 2;
    size_t k0 = (size_t)s * kChunk;
    float2 acc[32];
#pragma unroll
    for (int mi = 0; mi < 32; ++mi) acc[mi] = make_float2(0.f, 0.f);
    const float* w = W + k0 * N + n;
    const float* a = AT + k0 * 32;
#pragma unroll 4
    for (int kk = 0; kk < kChunk; ++kk) {
        float2 wv = *(const float2*)w;
#pragma unroll
        for (int mi = 0; mi < 32; ++mi) {
            float am = a[mi];
            acc[mi].x = fmaf(am, wv.x, acc[mi].x);
            acc[mi].y = fmaf(am, wv.y, acc[mi].y);
        }
        w += N;
        a += 32;
    }
    float* p = P + ((size_t)s * 32) * N + n;
#pragma unroll
    for (int mi = 0; mi < 32; ++mi)
        *(float2*)(p + (size_t)mi * N) = acc[mi];
}

// ---- phase 2: QKV gemm (768 blocks) + fc_in gemm (512 blocks) ----
__global__ __launch_bounds__(256) void phase2_kernel(const float* __restrict__ hT,
    const float* __restrict__ wq, const float* __restrict__ wk, const float* __restrict__ wv,
    float* __restrict__ Pq, const float* __restrict__ fciw, float* __restrict__ P1)
{
    int id = blockIdx.x;
    if (id < 768) {
        int w = id >> 8;
        const float* W = (w == 0) ? wq : (w == 1) ? wk : wv;
        float* Pz = Pq + (size_t)w * ((size_t)32 * 32 * NEMB);
        gemm_body(hT, W, Pz, NEMB, 128, id & 7, (id >> 3) & 31);
    } else {
        id -= 768;
        gemm_body(hT, fciw, P1, NINT, 256, id & 31, id >> 5);
    }
}

__device__ inline float gelu_tanh(float x)
{
    float x3 = x * x * x;
    return 0.5f * x * (1.f + tanhf(0.7978845608028654f * (x + 0.044715f * x3)));
}

// ---- phase 3: QKV reduce+RoPE (768 blocks) + fc_in reduce+gelu (2048 blocks) ----
__global__ __launch_bounds__(256) void phase3_kernel(const float* __restrict__ Pq,
    float* __restrict__ q, float* __restrict__ k, float* __restrict__ v,
    const int* __restrict__ pos,
    const float* __restrict__ P1, const float* __restrict__ fcib, float* __restrict__ mT)
{
    int id = blockIdx.x, t = threadIdx.x;
    if (id < 768) {
        int w = id >> 8;
        int m = (id >> 3) & 31;
        int n0 = ((id & 7) * 256 + t) * 2;
        const float* p = Pq + (size_t)w * ((size_t)32 * 32 * NEMB) + (size_t)m * NEMB + n0;
        float sx = 0.f, sy = 0.f;
#pragma unroll 4
        for (int i = 0; i < 32; ++i) {
            float2 u = *(const float2*)p;
            sx += u.x; sy += u.y;
            p += (size_t)32 * NEMB;
        }
        int d = n0 & (DD - 1);
        if (w < 2 && d < RDIM) {
            int i = d >> 1;
            float fr = exp2f((float)i * (-13.287712379549449f / 32.f)); // 10000^(-i/32)
            float ang = (float)pos[m] * fr;
            float sn, cs;
            sincosf(ang, &sn, &cs);
            float x1 = sx, x2 = sy;
            sx = x1 * cs - x2 * sn;
            sy = x2 * cs + x1 * sn;
        }
        float* o = (w == 0) ? q : (w == 1) ? k : v;
        *(float2*)(o + (size_t)m * NEMB + n0) = make_float2(sx, sy);
    } else {
        int j = id - 768;
        int m = j >> 6;
        int n = (j & 63) * 256 + t;
        const float* p = P1 + (size_t)m * NINT + n;
        float s = 0.f;
#pragma unroll 4
        for (int i = 0; i < 16; ++i) { s += *p; p += (size_t)32 * NINT; }
        mT[(size_t)n * 32 + m] = gelu_tanh(s + fcib[n]);
    }
}

// ---- phase 4: fc_out gemm (2048 blocks, FIRST) + attention partials (8192 1-wave blocks,
//      XCD-group swizzled so all 16 h-blocks of one (b,c) land on one XCD) ----
__global__ __launch_bounds__(64) void phase4_kernel(const float* __restrict__ q,
    const float* __restrict__ knew, const float* __restrict__ vnew,
    const float* __restrict__ kcache, const float* __restrict__ vcache,
    const int* __restrict__ kidx, const int* __restrict__ vidx,
    const int* __restrict__ nkl, const int* __restrict__ nvl,
    const float* __restrict__ mask,
    float* __restrict__ pm, float* __restrict__ pl, float* __restrict__ pctx,
    const float* __restrict__ mT, const float* __restrict__ fcow, float* __restrict__ P2)
{
    int id = blockIdx.x;
    int t = threadIdx.x;
    if (id < 2048) {
        // fc_out: N=4096, K=16384; x in [0,32), s in [0,64) chunk 256
        gemm_body64(mT, fcow, P2, NEMB, 256, id & 31, id >> 5);
        return;
    }
    int a = id - 2048;                 // 0..8191, a%8 == blockIdx%8 (2048 ≡ 0 mod 8)
    int x = a & 7;                     // XCD slot (round-robin heuristic)
    int j = a >> 3;                    // 0..1023
    int h = j & 15;                    // head
    int g = (j >> 4) * 8 + x;          // group = (b,c), all 16 h-blocks share x
    int b = g >> 4, c = g & 15;
    int bh = b * HH + h;

    __shared__ const float* kparr[CH];
    __shared__ const float* vparr[CH];
    __shared__ float sc[CH];

    // lane = one KV row: pointer setup with cache-override scan
    {
        int ks = kidx[b * KVLEN + c * CH + t];
        int vs = vidx[b * KVLEN + c * CH + t];
        const float* kbase = kcache + (size_t)ks * NEMB;
        const float* vbase = vcache + (size_t)vs * NEMB;
#pragma unroll
        for (int jj = 0; jj < BB; ++jj) {
            if (nkl[jj] == ks) kbase = knew + (size_t)jj * NEMB;
            if (nvl[jj] == vs) vbase = vnew + (size_t)jj * NEMB;
        }
        kparr[t] = kbase + (size_t)h * DD;
        vparr[t] = vbase + (size_t)h * DD;
    }
    __syncthreads();

    int u = t & 15, g4 = t >> 4;   // 16-lane group; lane covers d = u*4 + jj*64
    float4 qf[4];
#pragma unroll
    for (int jj = 0; jj < 4; ++jj) qf[jj] = *(const float4*)(q + (size_t)b * NEMB + (size_t)h * DD + u * 4 + jj * 64);

    // QK: 4 rows at a time (one per group), 16 iterations covering 64 rows
#pragma unroll 4
    for (int it = 0; it < 16; ++it) {
        int l = it * 4 + g4;
        const float* kr = kparr[l];
        float d = 0.f;
#pragma unroll
        for (int jj = 0; jj < 4; ++jj) {
            float4 kf = *(const float4*)(kr + u * 4 + jj * 64);
            d = fmaf(kf.x, qf[jj].x, fmaf(kf.y, qf[jj].y, fmaf(kf.z, qf[jj].z, fmaf(kf.w, qf[jj].w, d))));
        }
        d += __shfl_xor(d, 8, 64);
        d += __shfl_xor(d, 4, 64);
        d += __shfl_xor(d, 2, 64);
        d += __shfl_xor(d, 1, 64);
        if (u == 0) sc[l] = d * 0.0625f + mask[b * KVLEN + c * CH + l];
    }
    __syncthreads();

    // in-wave softmax over the 64 rows (row = lane)
    float sv = sc[t];
    float mx = sv;
#pragma unroll
    for (int o = 32; o > 0; o >>= 1) mx = fmaxf(mx, __shfl_xor(mx, o, 64));
    float e = expf(sv - mx);
    float sm = e;
#pragma unroll
    for (int o = 32; o > 0; o >>= 1) sm += __shfl_xor(sm, o, 64);

    // PV: lane owns d = t*4..t*4+3; V row pointer broadcast from LDS, weight from shfl
    float4 a4 = make_float4(0.f, 0.f, 0.f, 0.f);
#pragma unroll 8
    for (int l = 0; l < CH; ++l) {
        const float* vr = vparr[l];
        float4 vf = *(const float4*)(vr + t * 4);
        float pw = __shfl(e, l, 64);
        a4.x = fmaf(pw, vf.x, a4.x);
        a4.y = fmaf(pw, vf.y, a4.y);
        a4.z = fmaf(pw, vf.z, a4.z);
        a4.w = fmaf(pw, vf.w, a4.w);
    }

    int pi = bh * NCH + c;
    *(float4*)(pctx + (size_t)pi * DD + t * 4) = a4;
    if (t == 0) { pm[pi] = mx; pl[pi] = sm; }
}

// ---- phase 5: attention combine (512 blocks) ----
__global__ __launch_bounds__(256) void attn_comb_kernel(const float* __restrict__ pm,
    const float* __restrict__ pl, const float* __restrict__ pctx,
    float* __restrict__ ctxT)
{
    int bh = blockIdx.x;
    int b = bh >> 4, h = bh & 15;
    int t = threadIdx.x;
    float M = -INFINITY;
#pragma unroll
    for (int c = 0; c < NCH; ++c) M = fmaxf(M, pm[bh * NCH + c]);
    float L = 0.f, acc = 0.f;
#pragma unroll
    for (int c = 0; c < NCH; ++c) {
        float wv = expf(pm[bh * NCH + c] - M);
        L += pl[bh * NCH + c] * wv;
        acc += pctx[((size_t)bh * NCH + c) * DD + t] * wv;
    }
    ctxT[((size_t)h * DD + t) * BB + b] = acc / L;
}

// ---- phase 6: Wo gemm (512 blocks) + fc_out reduce -> mlp_tmp (512 blocks) ----
__global__ __launch_bounds__(256) void phase6_kernel(const float* __restrict__ ctxT,
    const float* __restrict__ wo, float* __restrict__ P0,
    const float* __restrict__ P2, const float* __restrict__ fcob,
    const float* __restrict__ resid, float* __restrict__ mlp_tmp)
{
    int id = blockIdx.x, t = threadIdx.x;
    if (id < 512) {
        gemm_body(ctxT, wo, P0, NEMB, 64, id & 7, id >> 3);
    } else {
        int j = id - 512;
        int m = j >> 4;
        int n = (j & 15) * 256 + t;
        const float* p = P2 + (size_t)m * NEMB + n;
        float s = 0.f;
#pragma unroll 4
        for (int i = 0; i < 64; ++i) { s += *p; p += (size_t)32 * NEMB; }
        mlp_tmp[(size_t)m * NEMB + n] = s + fcob[n] + resid[(size_t)m * NEMB + n];
    }
}

// ---- phase 7: Wo reduce + mlp_tmp -> out (512 blocks) ----
__global__ __launch_bounds__(256) void phase7_kernel(const float* __restrict__ P0,
    const float* __restrict__ mlp_tmp, float* __restrict__ out)
{
    int n = blockIdx.x * 256 + threadIdx.x;
    int m = blockIdx.y;
    const float* p = P0 + (size_t)m * NEMB + n;
    float s = 0.f;
#pragma unroll 4
    for (int i = 0; i < 64; ++i) { s += *p; p += (size_t)32 * NEMB; }
    out[(size_t)m * NEMB + n] = s + mlp_tmp[(size_t)m * NEMB + n];
}

extern "C" void kernel_launch(void* const* d_in, const int* in_sizes, int n_in,
                              void* d_out, int out_size, void* d_ws, size_t ws_size,
                              hipStream_t stream)
{
    (void)in_sizes; (void)n_in; (void)out_size; (void)ws_size;
    const float* hs      = (const float*)d_in[0];
    const float* kcache  = (const float*)d_in[1];
    const float* vcache  = (const float*)d_in[2];
    const float* ln_w    = (const float*)d_in[3];
    const float* ln_b    = (const float*)d_in[4];
    const float* wq      = (const float*)d_in[5];
    const float* wk      = (const float*)d_in[6];
    const float* wv      = (const float*)d_in[7];
    const float* wo      = (const float*)d_in[8];
    const float* fc_in_w = (const float*)d_in[9];
    const float* fc_in_b = (const float*)d_in[10];
    const float* fc_out_w= (const float*)d_in[11];
    const float* fc_out_b= (const float*)d_in[12];
    const float* mask    = (const float*)d_in[13];
    const int* nkl       = (const int*)d_in[14];
    const int* nvl       = (const int*)d_in[15];
    const int* kidx      = (const int*)d_in[16];
    const int* vidx      = (const int*)d_in[17];
    const int* pos       = (const int*)d_in[18];
    float* out = (float*)d_out;

    char* ws = (char*)d_ws;
    float* hT      = (float*)ws; ws += (size_t)NEMB * BB * 4;
    float* qb      = (float*)ws; ws += (size_t)BB * NEMB * 4;
    float* kb      = (float*)ws; ws += (size_t)BB * NEMB * 4;
    float* vb      = (float*)ws; ws += (size_t)BB * NEMB * 4;
    float* ctxT    = (float*)ws; ws += (size_t)NEMB * BB * 4;
    float* mlp_tmp = (float*)ws; ws += (size_t)BB * NEMB * 4;
    float* mT      = (float*)ws; ws += (size_t)NINT * BB * 4;
    float* pm      = (float*)ws; ws += (size_t)BB * HH * NCH * 4;
    float* pl      = (float*)ws; ws += (size_t)BB * HH * NCH * 4;
    float* pctx    = (float*)ws; ws += (size_t)BB * HH * NCH * DD * 4;
    float* Pq      = (float*)ws; ws += (size_t)3 * 32 * 32 * NEMB * 4;   // 50.3 MB
    float* P0      = (float*)ws; ws += (size_t)64 * 32 * NEMB * 4;       // 33.6 MB
    float* P1      = (float*)ws; ws += (size_t)16 * 32 * NINT * 4;       // 33.6 MB
    float* P2      = (float*)ws;                                          // 33.6 MB

    ln_kernel<<<BB, 256, 0, stream>>>(hs, ln_w, ln_b, hT);

    phase2_kernel<<<1280, 256, 0, stream>>>(hT, wq, wk, wv, Pq, fc_in_w, P1);

    phase3_kernel<<<2816, 256, 0, stream>>>(Pq, qb, kb, vb, pos, P1, fc_in_b, mT);

    phase4_kernel<<<10240, 64, 0, stream>>>(qb, kb, vb, kcache, vcache,
                                            kidx, vidx, nkl, nvl, mask,
                                            pm, pl, pctx, mT, fc_out_w, P2);

    attn_comb_kernel<<<BB * HH, 256, 0, stream>>>(pm, pl, pctx, ctxT);

    phase6_kernel<<<1024, 256, 0, stream>>>(ctxT, wo, P0, P2, fc_out_b, hs, mlp_tmp);

    phase7_kernel<<<dim3(16, 32), 256, 0, stream>>>(P0, mlp_tmp, out);
}